// Round 12
// baseline (272.494 us; speedup 1.0000x reference)
//
#include <hip/hip_runtime.h>
#include <type_traits>

typedef __bf16 bfrag __attribute__((ext_vector_type(8)));
typedef float f32x4 __attribute__((ext_vector_type(4)));
typedef float f32x16 __attribute__((ext_vector_type(16)));
typedef unsigned short us8 __attribute__((ext_vector_type(8)));
typedef unsigned short us4 __attribute__((ext_vector_type(4)));
typedef unsigned int u32x2 __attribute__((ext_vector_type(2)));
typedef unsigned int u32x4 __attribute__((ext_vector_type(4)));

__device__ __forceinline__ float bf2f(unsigned short s) {
  unsigned u = ((unsigned)s) << 16;
  float f;
  __builtin_memcpy(&f, &u, 4);
  return f;
}
__device__ __forceinline__ unsigned short f2bf(float f) {
  unsigned u;
  __builtin_memcpy(&u, &f, 4);
  u += 0x7fffu + ((u >> 16) & 1u);
  return (unsigned short)(u >> 16);
}
__device__ __forceinline__ float rdf(const void* p, size_t i, int isf) {
  return isf ? ((const float*)p)[i] : bf2f(((const unsigned short*)p)[i]);
}
__device__ __forceinline__ void gld16(const unsigned short* g, unsigned short* l) {
  __builtin_amdgcn_global_load_lds(
      (const __attribute__((address_space(1))) unsigned int*)g,
      (__attribute__((address_space(3))) unsigned int*)l, 16, 0, 0);
}
__device__ __forceinline__ unsigned cvtpk_bf16(float a, float b) {
  unsigned d;
  asm("v_cvt_pk_bf16_f32 %0, %1, %2" : "=v"(d) : "v"(a), "v"(b));
  return d;  // low16 = bf16(a), high16 = bf16(b)
}

// -------- layernorm unit: 4 tokens (1/wave) ----------------------------
template <int XMODE>
__device__ void norm_unit(const void* xin, const void* alpha, const void* beta,
                          unsigned short* out, int isf, int u) {
  constexpr int E = 512;
  int xf = XMODE ? 1 : isf;
  int tid = threadIdx.x;
  int wave = tid >> 6, lane = tid & 63;
  size_t tok = (size_t)u * 4 + wave;
  float v[8];
  if (xf) {
    const float* xp = (const float*)xin + tok * E + lane * 8;
    float4 a0 = *(const float4*)xp;
    float4 a1 = *(const float4*)(xp + 4);
    v[0] = a0.x; v[1] = a0.y; v[2] = a0.z; v[3] = a0.w;
    v[4] = a1.x; v[5] = a1.y; v[6] = a1.z; v[7] = a1.w;
  } else {
    us8 uu = *(const us8*)((const unsigned short*)xin + tok * E + lane * 8);
#pragma unroll
    for (int j = 0; j < 8; j++) v[j] = bf2f(uu[j]);
  }
  float s = 0.f, sq = 0.f;
#pragma unroll
  for (int j = 0; j < 8; j++) { s += v[j]; sq += v[j] * v[j]; }
#pragma unroll
  for (int off = 1; off < 64; off <<= 1) {
    s += __shfl_xor(s, off, 64);
    sq += __shfl_xor(sq, off, 64);
  }
  float mean = s * (1.0f / 512.0f);
  float var = fmaxf((sq - 512.0f * mean * mean) * (1.0f / 511.0f), 0.0f);
  float inv = rdf(alpha, 0, isf) / (sqrtf(var) + 1e-6f);
  float be = rdf(beta, 0, isf);
  us8 ov;
#pragma unroll
  for (int j = 0; j < 8; j++) ov[j] = f2bf((v[j] - mean) * inv + be);
  *(us8*)(out + tok * E + lane * 8) = ov;
}

// ---------------- setup: self-detect + weight transposes + bcat + norm1 --
__global__ __launch_bounds__(256) void setup_k(
    const unsigned short* __restrict__ x16,
    const void* wq, const void* wk, const void* wv, const void* wo,
    const void* w1, const void* w2,
    unsigned short* wqkvT, unsigned short* woT,
    unsigned short* w1T, unsigned short* w2T,
    const void* bq, const void* bk, const void* bv, const void* bo,
    const void* b1, const void* b2, float* __restrict__ bcat,
    const void* alpha1, const void* beta1, unsigned short* __restrict__ n1,
    int* __restrict__ flag) {
  __shared__ unsigned short tile[32][33];
  __shared__ int s_cnt;
  int tid = threadIdx.x;
  int bid = blockIdx.x;
  if (tid == 0) s_cnt = 0;
  __syncthreads();
  {
    int c = 0;
    for (int i = tid; i < 4096; i += 256) {
      unsigned short s = x16[2 * i];
      int e = (s >> 7) & 0xFF;
      if (e > 0xC2 || (e != 0 && e < 0x3D)) c++;
    }
    atomicAdd(&s_cnt, c);
  }
  __syncthreads();
  const int isf = (s_cnt > 256) ? 1 : 0;
  if (bid == 0 && tid == 0) flag[0] = isf;

  if (bid >= 3090) {  // norm1
    norm_unit<0>(x16, alpha1, beta1, n1, isf, bid - 3090);
    return;
  }
  if (bid >= 3072) {  // bias concat
    int i = (bid - 3072) * 256 + tid;
    if (i < 4608) {
      float v;
      if (i < 512) v = rdf(bq, i, isf);
      else if (i < 1024) v = rdf(bk, i - 512, isf);
      else if (i < 1536) v = rdf(bv, i - 1024, isf);
      else if (i < 2048) v = rdf(bo, i - 1536, isf);
      else if (i < 4096) v = rdf(b1, i - 2048, isf);
      else v = rdf(b2, i - 4096, isf);
      bcat[i] = v;
    }
    return;
  }
  const void* W;
  unsigned short* Wt;
  int K, N, t;
  if (bid < 1024) {
    K = 512; N = 512; t = bid & 255;
    if (bid < 256) { W = wq; Wt = wqkvT; }
    else if (bid < 512) { W = wk; Wt = wqkvT + 262144; }
    else if (bid < 768) { W = wv; Wt = wqkvT + 524288; }
    else { W = wo; Wt = woT; }
  } else if (bid < 2048) {
    W = w1; Wt = w1T; K = 512; N = 2048; t = bid - 1024;
  } else {
    W = w2; Wt = w2T; K = 2048; N = 512; t = bid - 2048;
  }
  int nx = N >> 5;
  int n0 = (t % nx) * 32, k0 = (t / nx) * 32;
#pragma unroll
  for (int i = 0; i < 4; i++) {
    int e = tid + i * 256;
    int r = e >> 5, c = e & 31;
    tile[r][c] = f2bf(rdf(W, (size_t)(k0 + r) * N + n0 + c, isf));
  }
  __syncthreads();
#pragma unroll
  for (int i = 0; i < 4; i++) {
    int e = tid + i * 256;
    int r = e >> 5, c = e & 31;
    Wt[(size_t)(n0 + r) * K + k0 + c] = tile[c][r];
  }
}

// ---------------- norm2 standalone (x1 f32 -> n2 bf16) ------------------
__global__ __launch_bounds__(256) void norm2_k(
    const void* __restrict__ xin, const void* __restrict__ alpha,
    const void* __restrict__ beta, unsigned short* __restrict__ out,
    const int* __restrict__ flag) {
  norm_unit<1>(xin, alpha, beta, out, flag[0], blockIdx.x);
}

// ---------------- GEMM: 128xTN tile, BK=64, XOR-swizzled LDS ------------
// R12: 2-phase DOUBLE-BUFFERED staging (in-session-proven attn pattern:
// STAGE next BEFORE compute; single end-of-iter barrier -> the vmcnt(0)
// drain lands AFTER compute, hiding staging latency in-block). At K=512
// only 8 K-iters run, so each exposed drain is ~8x more significant than
// at the 4096^3 shapes where explicit dbuf measured null (m99/m100).
// TN=64: LDS 48KB keeps 3 blocks/CU (pure upside). TN=128: 64KB -> 2/CU
// (overlap vs occupancy trade). Swapped MFMA epilogue (R11, neutral):
// lane holds 4 consecutive n -> vector epilogue loads/stores.
// QSC: scale n<512 by 0.18033688 (0.125*log2e) f32-exact (attn fold).
// VT: QKV V-third transposes via LDS (pitch 136, fits the 64KB union).
template <int TN, int RES, int OUTM, int RELU, int QSC, int VT>
__global__ __launch_bounds__(256, (TN == 128) ? 2 : 3) void gemm2_k(
    const unsigned short* __restrict__ A,
    const unsigned short* __restrict__ Bt,
    const float* __restrict__ bias,
    const void* __restrict__ res,
    void* __restrict__ outp,
    unsigned short* __restrict__ vbt,
    int N, int K, const int* __restrict__ flag) {
  constexpr int MT = (TN == 128) ? 4 : 2;
  constexpr int BROWS = TN / 4;   // Bs rows staged per wave
  constexpr int ASZ = 128 * 64;
  constexpr int BSZ = TN * 64;
  constexpr int HALF = ASZ + BSZ;
  __shared__ alignas(16) unsigned short smem[2 * HALF];  // dbuf A|B pairs
  int isf = flag[0];
  int outf32 = (OUTM == 1) || (OUTM == 2 && isf);
  int tid = threadIdx.x;
  int wave = tid >> 6, lane = tid & 63;
  int quad = lane >> 4, l16 = lane & 15, l7 = l16 & 7;
  int wm = (TN == 128) ? (wave >> 1) : wave;
  int wn = (TN == 128) ? (wave & 1) : 0;
  size_t m0 = (size_t)blockIdx.x * 128;
  size_t n0 = (size_t)blockIdx.y * TN;

  int lrow = lane >> 3;                 // 0..7
  int gcol = 8 * ((lane & 7) ^ lrow);   // swizzled source chunk (shorts)

  const unsigned short* ag = A + (m0 + wave * 32 + lrow) * K + gcol;
  const unsigned short* bg = Bt + (n0 + wave * BROWS + lrow) * K + gcol;

  auto STAGE = [&](int buf, int k0) {
    unsigned short* asl = smem + buf * HALF + (wave * 32) * 64;
    unsigned short* bsl = smem + buf * HALF + ASZ + (wave * BROWS) * 64;
#pragma unroll
    for (int c = 0; c < 4; c++)
      gld16(ag + (size_t)(8 * c) * K + k0, asl + (8 * c) * 64);
#pragma unroll
    for (int c = 0; c < BROWS / 8; c++)
      gld16(bg + (size_t)(8 * c) * K + k0, bsl + (8 * c) * 64);
  };

  f32x4 acc[MT][4];
#pragma unroll
  for (int i = 0; i < MT; i++)
#pragma unroll
    for (int j = 0; j < 4; j++) acc[i][j] = {0.f, 0.f, 0.f, 0.f};

  STAGE(0, 0);
  __syncthreads();  // tile 0 staged (vmcnt drained)
  int nk = K >> 6;
  for (int it = 0; it < nk; ++it) {
    int cur = it & 1;
    if (it + 1 < nk) STAGE(cur ^ 1, (it + 1) << 6);  // in flight over compute
    const unsigned short* Ac = smem + cur * HALF;
    const unsigned short* Bc = smem + cur * HALF + ASZ;
#pragma unroll
    for (int ko = 0; ko < 2; ko++) {
      int slot = ((4 * ko + quad) ^ l7) * 8;
      bfrag af[MT], bf[4];
#pragma unroll
      for (int i = 0; i < MT; i++)
        af[i] = *(const bfrag*)&Ac[(wm * (MT * 16) + i * 16 + l16) * 64 + slot];
#pragma unroll
      for (int j = 0; j < 4; j++)
        bf[j] = *(const bfrag*)&Bc[(wn * 64 + j * 16 + l16) * 64 + slot];
#pragma unroll
      for (int i = 0; i < MT; i++)
#pragma unroll
        for (int j = 0; j < 4; j++)
          acc[i][j] = __builtin_amdgcn_mfma_f32_16x16x32_bf16(bf[j], af[i], acc[i][j], 0, 0, 0);
    }
    __syncthreads();  // next tile staged + all reads of cur done
  }
  // swapped layout: m = m0+wm*(MT*16)+i*16+l16 ; n = n0+wn*64+j*16+quad*4+r
  if (VT && n0 >= 1024) {
    // V third of QKV: transpose 128x128 panel through LDS, then write
    // vbt[(b*8+hh)*64+d][s] with 64B-contiguous segments along s.
#pragma unroll
    for (int j = 0; j < 4; j++) {
      int nl = wn * 64 + j * 16 + quad * 4;
      float4 bv = *(const float4*)&bias[n0 + nl];
#pragma unroll
      for (int i = 0; i < MT; i++) {
        int ml = wm * (MT * 16) + i * 16 + l16;
        smem[(nl + 0) * 136 + ml] = f2bf(acc[i][j][0] + bv.x);
        smem[(nl + 1) * 136 + ml] = f2bf(acc[i][j][1] + bv.y);
        smem[(nl + 2) * 136 + ml] = f2bf(acc[i][j][2] + bv.z);
        smem[(nl + 3) * 136 + ml] = f2bf(acc[i][j][3] + bv.w);
      }
    }
    __syncthreads();
    int b_ = (int)(m0 >> 11);
    int sbase = (int)(m0 & 2047);
    int rel0 = (int)n0 - 1024;
#pragma unroll
    for (int it2 = 0; it2 < 8; it2++) {
      int nl = (tid >> 2) + 64 * (it2 & 1);
      int mc = (tid & 3) + 4 * (it2 >> 1);
      int rel = rel0 + nl;
      size_t row = ((size_t)(b_ * 8 + (rel >> 6)) * 64 + (rel & 63)) * 2048;
      us8 v = *(const us8*)&smem[nl * 136 + mc * 8];
      *(us8*)&vbt[row + sbase + mc * 8] = v;
    }
    return;
  }
#pragma unroll
  for (int j = 0; j < 4; j++) {
    int nl = wn * 64 + j * 16 + quad * 4;
    size_t n = n0 + nl;
    float4 bv = *(const float4*)&bias[n];
#pragma unroll
    for (int i = 0; i < MT; i++) {
      size_t m = m0 + wm * (MT * 16) + i * 16 + l16;
      size_t off = m * N + n;
      float v0 = acc[i][j][0] + bv.x;
      float v1 = acc[i][j][1] + bv.y;
      float v2 = acc[i][j][2] + bv.z;
      float v3 = acc[i][j][3] + bv.w;
      if (QSC && n < 512) {
        v0 *= 0.18033688f; v1 *= 0.18033688f;
        v2 *= 0.18033688f; v3 *= 0.18033688f;
      }
      if (RELU) {
        v0 = fmaxf(v0, 0.0f); v1 = fmaxf(v1, 0.0f);
        v2 = fmaxf(v2, 0.0f); v3 = fmaxf(v3, 0.0f);
      }
      if (RES == 1) {
        if (isf) {
          float4 rr = *(const float4*)&((const float*)res)[off];
          v0 += rr.x; v1 += rr.y; v2 += rr.z; v3 += rr.w;
        } else {
          us4 rr = *(const us4*)&((const unsigned short*)res)[off];
          v0 += bf2f(rr[0]); v1 += bf2f(rr[1]);
          v2 += bf2f(rr[2]); v3 += bf2f(rr[3]);
        }
      } else if (RES == 2) {
        float4 rr = *(const float4*)&((const float*)res)[off];
        v0 += rr.x; v1 += rr.y; v2 += rr.z; v3 += rr.w;
      }
      if (outf32) {
        float4 o4 = {v0, v1, v2, v3};
        *(float4*)&((float*)outp)[off] = o4;
      } else {
        us4 o4 = {f2bf(v0), f2bf(v1), f2bf(v2), f2bf(v3)};
        *(us4*)&((unsigned short*)outp)[off] = o4;
      }
    }
  }
}

// ---------------- flash attention: 64q/wave, key-split, 8 waves ---------
// R7-proven kernel (53us). 256 blocks x 512 thr, 8 waves = 4 q-subblocks
// x 2 key-halves, 64 q/wave. Q pre-scaled by 0.125*log2e in QKV gemm ->
// softmax = exp2(pacc). Key-split merge via LDS (exact, no-max softmax).
// XCD chunk: 4 bh/XCD (2MB L2 set; K/V ARE HBM/L2-sensitive, unlike GEMM).
__global__ __launch_bounds__(512) void attn_k(
    const unsigned short* __restrict__ qkb,  // [8192][1536] q|k|v (q scaled)
    const unsigned short* __restrict__ vbt,  // [32*64][2048] = V^T per bh
    const int* __restrict__ mask,
    unsigned short* __restrict__ ctx) {      // [8192][512]
  constexpr int S = 2048;
  __shared__ alignas(16) unsigned short Kt[2][2][64 * 64];  // [kh][buf] 32 KB
  __shared__ alignas(16) unsigned short Vt[2][2][64 * 64];  // [kh][buf] 32 KB
  __shared__ alignas(16) float mskf[S];                     // 8 KB
  __shared__ float ml[2][256];                              // 2 KB
  __shared__ int s_all;
  int tid = threadIdx.x, wave = tid >> 6, lane = tid & 63;
  int kh = wave >> 2, wv = wave & 3;
  int l32 = lane & 31, hi = lane >> 5;

  // XCD-aware work mapping (256 blocks, 8 XCDs round-robin by linear id)
  int lin = blockIdx.x;
  int work = (lin & 7) * 32 + (lin >> 3);
  int bh = work >> 3;          // 0..31 (4 consecutive bh per XCD)
  int q0 = (work & 7) * 256;   // 0..1792
  int b = bh >> 3, h = bh & 7;
  size_t rowbase = (size_t)b * S;

  // Q fragments (B-operand), 2 q-groups of 32: col=q=l32, k(d)=16ds+8hi+j
  bfrag qf[2][4];
#pragma unroll
  for (int qg = 0; qg < 2; qg++) {
    const unsigned short* qp =
        qkb + (rowbase + q0 + wv * 64 + qg * 32 + l32) * 1536 + h * 64 + hi * 8;
#pragma unroll
    for (int ds = 0; ds < 4; ds++) qf[qg][ds] = *(const bfrag*)(qp + ds * 16);
  }

  int srow_l = lane >> 3;  // 0..7; equals (staged row)&7 -> swizzle const/lane
  int sc = lane & 7;
  int swz = (sc ^ srow_l) * 8;
  const unsigned short* kgb = qkb + 512 + h * 64;
  const unsigned short* vgb = vbt + (size_t)bh * 64 * S;

  // staging pointers (strength-reduced); wave stages 16 rows of its half
  const unsigned short* kp[2];
  const unsigned short* vp[2];
#pragma unroll
  for (int i = 0; i < 2; i++) {
    int r = wv * 16 + i * 8 + srow_l;
    kp[i] = kgb + (rowbase + kh * 1024 + r) * 1536 + swz;
    vp[i] = vgb + (size_t)r * S + kh * 1024 + swz;
  }

  auto STAGE = [&](int buf) {
#pragma unroll
    for (int i = 0; i < 2; i++) {
      gld16(kp[i], &Kt[kh][buf][(wv * 16 + i * 8) * 64]);
      kp[i] += 64 * 1536;
      gld16(vp[i], &Vt[kh][buf][(wv * 16 + i * 8) * 64]);
      vp[i] += 64;
    }
  };

  f32x16 o[4];  // [qg*2+dt]
#pragma unroll
  for (int i = 0; i < 4; i++)
#pragma unroll
    for (int j = 0; j < 16; j++) o[i][j] = 0.f;
  float l_i[2] = {0.f, 0.f};

  STAGE(0);
  if (tid == 0) s_all = 1;
  __syncthreads();
  {
    int ok = 1;
    for (int i = tid; i < S; i += 512) {
      int mv = mask[rowbase + i];
      ok &= (mv != 0);
      mskf[i] = mv ? 0.0f : -1e5f;
    }
    atomicAnd(&s_all, ok);
  }
  __syncthreads();  // tile 0 + mask + s_all ready
  int am = s_all;

  auto BODY = [&](auto amc) {
    constexpr bool AM = decltype(amc)::value;
    for (int it = 0; it < 16; it++) {
      int cur = it & 1;
      if (it + 1 < 16) STAGE(cur ^ 1);  // in flight across whole compute

#pragma unroll
      for (int qg = 0; qg < 2; qg++) {
#pragma unroll
        for (int t = 0; t < 2; t++) {
          // ---- QK^T (swapped): pacc = D[key in sub-tile t][q] ----
          f32x16 pacc;
          {
            int r = t * 32 + l32;
            f32x16 z = {};
#pragma unroll
            for (int ds = 0; ds < 4; ds++) {
              int phys = ((2 * ds + hi) ^ (l32 & 7)) * 8;
              bfrag kf = *(const bfrag*)&Kt[kh][cur][r * 64 + phys];
              pacc = __builtin_amdgcn_mfma_f32_32x32x16_bf16(
                  kf, qf[qg][ds], ds == 0 ? z : pacc, 0, 0, 0);
            }
          }
          // ---- softmax (Q pre-scaled): key=(reg&3)+8*(reg>>2)+4*hi+32t --
          unsigned pb[8];
#pragma unroll
          for (int g = 0; g < 4; g++) {
            float p0, p1, p2, p3;
            if constexpr (AM) {
              p0 = __builtin_amdgcn_exp2f(pacc[g * 4 + 0]);
              p1 = __builtin_amdgcn_exp2f(pacc[g * 4 + 1]);
              p2 = __builtin_amdgcn_exp2f(pacc[g * 4 + 2]);
              p3 = __builtin_amdgcn_exp2f(pacc[g * 4 + 3]);
            } else {
              float4 m4 =
                  *(const float4*)&mskf[kh * 1024 + it * 64 + t * 32 + g * 8 + hi * 4];
              p0 = __builtin_amdgcn_exp2f(pacc[g * 4 + 0] + m4.x);
              p1 = __builtin_amdgcn_exp2f(pacc[g * 4 + 1] + m4.y);
              p2 = __builtin_amdgcn_exp2f(pacc[g * 4 + 2] + m4.z);
              p3 = __builtin_amdgcn_exp2f(pacc[g * 4 + 3] + m4.w);
            }
            l_i[qg] += (p0 + p1) + (p2 + p3);
            pb[g * 2] = cvtpk_bf16(p0, p1);
            pb[g * 2 + 1] = cvtpk_bf16(p2, p3);
          }
          // ---- PV for this sub-tile: ks = 2t+e ----
#pragma unroll
          for (int e = 0; e < 2; e++) {
            u32x2 sA = __builtin_amdgcn_permlane32_swap(
                pb[4 * e + 0], pb[4 * e + 2], false, false);
            u32x2 sB = __builtin_amdgcn_permlane32_swap(
                pb[4 * e + 1], pb[4 * e + 3], false, false);
            u32x4 pw = {sA.x, sB.x, sA.y, sB.y};
            bfrag pf = __builtin_bit_cast(bfrag, pw);
            int ks = 2 * t + e;
#pragma unroll
            for (int dt = 0; dt < 2; dt++) {
              int r = dt * 32 + l32;
              int phys = ((2 * ks + hi) ^ (l32 & 7)) * 8;
              bfrag vf = *(const bfrag*)&Vt[kh][cur][r * 64 + phys];
              o[qg * 2 + dt] = __builtin_amdgcn_mfma_f32_32x32x16_bf16(
                  pf, vf, o[qg * 2 + dt], 0, 0, 0);
            }
          }
        }
      }
      __syncthreads();  // next tile staged + all reads of cur done
    }
  };
  if (am) BODY(std::integral_constant<bool, true>{});
  else    BODY(std::integral_constant<bool, false>{});

  // ---- merge halves through LDS, normalize, store ----
#pragma unroll
  for (int qg = 0; qg < 2; qg++) {
    unsigned lu = __builtin_bit_cast(unsigned, l_i[qg]);
    u32x2 lr = __builtin_amdgcn_permlane32_swap(lu, lu, false, false);
    float l_tot = __builtin_bit_cast(float, lr.x) + __builtin_bit_cast(float, lr.y);
    if (lane < 32) ml[kh][wv * 64 + qg * 32 + l32] = l_tot;
  }
  float* mrgK = (float*)&Kt[0][0][0];  // 32 KB: 256q x 32d (dt=0), K dead
  float* mrgV = (float*)&Vt[0][0][0];  // 32 KB: 256q x 32d (dt=1), V dead
  if (kh == 1) {
#pragma unroll
    for (int qg = 0; qg < 2; qg++) {
#pragma unroll
      for (int reg = 0; reg < 16; reg++) {
        int ql = (reg & 3) + 8 * (reg >> 2) + 4 * hi;
        int qi = wv * 64 + qg * 32 + ql;
        mrgK[qi * 32 + l32] = o[qg * 2 + 0][reg];
        mrgV[qi * 32 + l32] = o[qg * 2 + 1][reg];
      }
    }
  }
  __syncthreads();
  if (kh == 0) {
#pragma unroll
    for (int qg = 0; qg < 2; qg++) {
#pragma unroll
      for (int reg = 0; reg < 16; reg++) {
        int ql = (reg & 3) + 8 * (reg >> 2) + 4 * hi;
        int qi = wv * 64 + qg * 32 + ql;
        float inv = 1.0f / fmaxf(ml[0][qi] + ml[1][qi], 1e-30f);
        size_t qrow = rowbase + q0 + qi;
        float v0 = (o[qg * 2 + 0][reg] + mrgK[qi * 32 + l32]) * inv;
        float v1 = (o[qg * 2 + 1][reg] + mrgV[qi * 32 + l32]) * inv;
        ctx[qrow * 512 + h * 64 + l32] = f2bf(v0);
        ctx[qrow * 512 + h * 64 + 32 + l32] = f2bf(v1);
      }
    }
  }
}

extern "C" void kernel_launch(void* const* d_in, const int* in_sizes, int n_in,
                              void* d_out, int out_size, void* d_ws, size_t ws_size,
                              hipStream_t stream) {
  const unsigned short* x = (const unsigned short*)d_in[0];
  const int* mask         = (const int*)d_in[1];
  const void* wq = d_in[2];  const void* bq = d_in[3];
  const void* wk = d_in[4];  const void* bk = d_in[5];
  const void* wv = d_in[6];  const void* bv = d_in[7];
  const void* wo = d_in[8];  const void* bo = d_in[9];
  const void* w1 = d_in[10]; const void* b1 = d_in[11];
  const void* w2 = d_in[12]; const void* b2 = d_in[13];
  const void* alpha1 = d_in[14]; const void* beta1 = d_in[15];
  const void* alpha2 = d_in[16]; const void* beta2 = d_in[17];

  char* ws = (char*)d_ws;
  int* flag            = (int*)(ws + 0);
  unsigned short* wqkvT= (unsigned short*)(ws + 65536);    // [1536][512]
  unsigned short* woT  = (unsigned short*)(ws + 1638400);
  unsigned short* w1T  = (unsigned short*)(ws + 2162688);  // [2048][512]
  unsigned short* w2T  = (unsigned short*)(ws + 4259840);  // [512][2048]
  float*          bcat = (float*)         (ws + 6356992);  // 4608 f32
  float*          x1   = (float*)         (ws + 6422528);  // [8192][512] f32
  unsigned short* n1   = (unsigned short*)(ws + 23199744); // also ctx, n2
  unsigned short* qkb  = (unsigned short*)(ws + 31588352); // [8192][1536]
  unsigned short* vbt  = (unsigned short*)(ws + 56754176); // [2048][2048]
  unsigned short* ff1  = qkb;                              // [8192][2048] overlay

  dim3 blk(256);

  setup_k<<<5138, blk, 0, stream>>>(x, wq, wk, wv, wo, w1, w2,
                                    wqkvT, woT, w1T, w2T,
                                    bq, bk, bv, bo, b1, b2, bcat,
                                    alpha1, beta1, n1, flag);
  // fused QKV (Q cols scaled; V third transposed via LDS direct to vbt)
  gemm2_k<128, 0, 0, 0, 1, 1><<<dim3(64, 12), blk, 0, stream>>>(n1, wqkvT, bcat, nullptr, qkb, vbt, 1536, 512, flag);
  attn_k<<<256, dim3(512), 0, stream>>>(qkb, vbt, mask, n1);
  // out projection + residual(x) -> x1 f32
  gemm2_k<64, 1, 1, 0, 0, 0><<<dim3(64, 8), blk, 0, stream>>>(n1, woT, bcat + 1536, (const void*)x, x1, nullptr, 512, 512, flag);
  norm2_k<<<2048, blk, 0, stream>>>(x1, alpha2, beta2, n1, flag);
  // ffn1 + relu -> ff1
  gemm2_k<128, 0, 0, 1, 0, 0><<<dim3(64, 16), blk, 0, stream>>>(n1, w1T, bcat + 2048, nullptr, ff1, nullptr, 2048, 512, flag);
  // ffn2 + residual(x1) -> d_out
  gemm2_k<64, 2, 2, 0, 0, 0><<<dim3(64, 8), blk, 0, stream>>>(ff1, w2T, bcat + 4096, x1, d_out, nullptr, 512, 2048, flag);
}

// Round 13
// 262.415 us; speedup vs baseline: 1.0384x; 1.0384x over previous
//
#include <hip/hip_runtime.h>
#include <type_traits>

typedef __bf16 bfrag __attribute__((ext_vector_type(8)));
typedef float f32x4 __attribute__((ext_vector_type(4)));
typedef float f32x16 __attribute__((ext_vector_type(16)));
typedef unsigned short us8 __attribute__((ext_vector_type(8)));
typedef unsigned short us4 __attribute__((ext_vector_type(4)));
typedef unsigned int u32x2 __attribute__((ext_vector_type(2)));
typedef unsigned int u32x4 __attribute__((ext_vector_type(4)));

__device__ __forceinline__ float bf2f(unsigned short s) {
  unsigned u = ((unsigned)s) << 16;
  float f;
  __builtin_memcpy(&f, &u, 4);
  return f;
}
__device__ __forceinline__ unsigned short f2bf(float f) {
  unsigned u;
  __builtin_memcpy(&u, &f, 4);
  u += 0x7fffu + ((u >> 16) & 1u);
  return (unsigned short)(u >> 16);
}
__device__ __forceinline__ float rdf(const void* p, size_t i, int isf) {
  return isf ? ((const float*)p)[i] : bf2f(((const unsigned short*)p)[i]);
}
__device__ __forceinline__ void gld16(const unsigned short* g, unsigned short* l) {
  __builtin_amdgcn_global_load_lds(
      (const __attribute__((address_space(1))) unsigned int*)g,
      (__attribute__((address_space(3))) unsigned int*)l, 16, 0, 0);
}
__device__ __forceinline__ unsigned cvtpk_bf16(float a, float b) {
  unsigned d;
  asm("v_cvt_pk_bf16_f32 %0, %1, %2" : "=v"(d) : "v"(a), "v"(b));
  return d;  // low16 = bf16(a), high16 = bf16(b)
}

// -------- layernorm unit: 4 tokens (1/wave) ----------------------------
template <int XMODE>
__device__ void norm_unit(const void* xin, const void* alpha, const void* beta,
                          unsigned short* out, int isf, int u) {
  constexpr int E = 512;
  int xf = XMODE ? 1 : isf;
  int tid = threadIdx.x;
  int wave = tid >> 6, lane = tid & 63;
  size_t tok = (size_t)u * 4 + wave;
  float v[8];
  if (xf) {
    const float* xp = (const float*)xin + tok * E + lane * 8;
    float4 a0 = *(const float4*)xp;
    float4 a1 = *(const float4*)(xp + 4);
    v[0] = a0.x; v[1] = a0.y; v[2] = a0.z; v[3] = a0.w;
    v[4] = a1.x; v[5] = a1.y; v[6] = a1.z; v[7] = a1.w;
  } else {
    us8 uu = *(const us8*)((const unsigned short*)xin + tok * E + lane * 8);
#pragma unroll
    for (int j = 0; j < 8; j++) v[j] = bf2f(uu[j]);
  }
  float s = 0.f, sq = 0.f;
#pragma unroll
  for (int j = 0; j < 8; j++) { s += v[j]; sq += v[j] * v[j]; }
#pragma unroll
  for (int off = 1; off < 64; off <<= 1) {
    s += __shfl_xor(s, off, 64);
    sq += __shfl_xor(sq, off, 64);
  }
  float mean = s * (1.0f / 512.0f);
  float var = fmaxf((sq - 512.0f * mean * mean) * (1.0f / 511.0f), 0.0f);
  float inv = rdf(alpha, 0, isf) / (sqrtf(var) + 1e-6f);
  float be = rdf(beta, 0, isf);
  us8 ov;
#pragma unroll
  for (int j = 0; j < 8; j++) ov[j] = f2bf((v[j] - mean) * inv + be);
  *(us8*)(out + tok * E + lane * 8) = ov;
}

// ---------------- setup: self-detect + weight transposes + bcat + norm1 --
// R13: transpose load/store vectorized (float4/us4; bf16 path is a raw
// copy -- f2bf(bf2f(x)) is identity). tile pitch 36 for 8B alignment.
__global__ __launch_bounds__(256) void setup_k(
    const unsigned short* __restrict__ x16,
    const void* wq, const void* wk, const void* wv, const void* wo,
    const void* w1, const void* w2,
    unsigned short* wqkvT, unsigned short* woT,
    unsigned short* w1T, unsigned short* w2T,
    const void* bq, const void* bk, const void* bv, const void* bo,
    const void* b1, const void* b2, float* __restrict__ bcat,
    const void* alpha1, const void* beta1, unsigned short* __restrict__ n1,
    int* __restrict__ flag) {
  __shared__ unsigned short tile[32][36];
  __shared__ int s_cnt;
  int tid = threadIdx.x;
  int bid = blockIdx.x;
  if (tid == 0) s_cnt = 0;
  __syncthreads();
  {
    int c = 0;
    for (int i = tid; i < 4096; i += 256) {
      unsigned short s = x16[2 * i];
      int e = (s >> 7) & 0xFF;
      if (e > 0xC2 || (e != 0 && e < 0x3D)) c++;
    }
    atomicAdd(&s_cnt, c);
  }
  __syncthreads();
  const int isf = (s_cnt > 256) ? 1 : 0;
  if (bid == 0 && tid == 0) flag[0] = isf;

  if (bid >= 3090) {  // norm1
    norm_unit<0>(x16, alpha1, beta1, n1, isf, bid - 3090);
    return;
  }
  if (bid >= 3072) {  // bias concat
    int i = (bid - 3072) * 256 + tid;
    if (i < 4608) {
      float v;
      if (i < 512) v = rdf(bq, i, isf);
      else if (i < 1024) v = rdf(bk, i - 512, isf);
      else if (i < 1536) v = rdf(bv, i - 1024, isf);
      else if (i < 2048) v = rdf(bo, i - 1536, isf);
      else if (i < 4096) v = rdf(b1, i - 2048, isf);
      else v = rdf(b2, i - 4096, isf);
      bcat[i] = v;
    }
    return;
  }
  const void* W;
  unsigned short* Wt;
  int K, N, t;
  if (bid < 1024) {
    K = 512; N = 512; t = bid & 255;
    if (bid < 256) { W = wq; Wt = wqkvT; }
    else if (bid < 512) { W = wk; Wt = wqkvT + 262144; }
    else if (bid < 768) { W = wv; Wt = wqkvT + 524288; }
    else { W = wo; Wt = woT; }
  } else if (bid < 2048) {
    W = w1; Wt = w1T; K = 512; N = 2048; t = bid - 1024;
  } else {
    W = w2; Wt = w2T; K = 2048; N = 512; t = bid - 2048;
  }
  int nx = N >> 5;
  int n0 = (t % nx) * 32, k0 = (t / nx) * 32;
  int r = tid >> 3, c0 = (tid & 7) * 4;  // 256 thr = 32 rows x 8 col-quads
  if (isf) {
    float4 w4 = *(const float4*)((const float*)W + (size_t)(k0 + r) * N + n0 + c0);
    tile[r][c0 + 0] = f2bf(w4.x);
    tile[r][c0 + 1] = f2bf(w4.y);
    tile[r][c0 + 2] = f2bf(w4.z);
    tile[r][c0 + 3] = f2bf(w4.w);
  } else {
    *(us4*)&tile[r][c0] =
        *(const us4*)((const unsigned short*)W + (size_t)(k0 + r) * N + n0 + c0);
  }
  __syncthreads();
  us4 o4;
  o4[0] = tile[c0 + 0][r];
  o4[1] = tile[c0 + 1][r];
  o4[2] = tile[c0 + 2][r];
  o4[3] = tile[c0 + 3][r];
  *(us4*)&Wt[(size_t)(n0 + r) * K + k0 + c0] = o4;
}

// ---------------- norm2 standalone (x1 f32 -> n2 bf16) ------------------
__global__ __launch_bounds__(256) void norm2_k(
    const void* __restrict__ xin, const void* __restrict__ alpha,
    const void* __restrict__ beta, unsigned short* __restrict__ out,
    const int* __restrict__ flag) {
  norm_unit<1>(xin, alpha, beta, out, flag[0], blockIdx.x);
}

// ---------------- GEMM: 128xTN tile, BK=64, XOR-swizzled LDS ------------
// R13: reverted to R11 single-buffered form (R12's 2-phase dbuf regressed:
// at 2-3 blocks/CU the co-resident block already covers the barrier drain
// -- same mechanism as attn R7 -- and TN=128 lost a block/CU to dbuf LDS).
// Swapped MFMA epilogue (R11, neutral-kept): lane holds 4 consecutive n
// -> vector epilogue loads/stores.
// QSC: scale n<512 by 0.18033688 (0.125*log2e) f32-exact (attn fold).
// VT: QKV V-third transposes via LDS (pitch 136) -> vbt, 64B stores.
template <int TN, int RES, int OUTM, int RELU, int QSC, int VT>
__global__ __launch_bounds__(256, 3) void gemm2_k(
    const unsigned short* __restrict__ A,
    const unsigned short* __restrict__ Bt,
    const float* __restrict__ bias,
    const void* __restrict__ res,
    void* __restrict__ outp,
    unsigned short* __restrict__ vbt,
    int N, int K, const int* __restrict__ flag) {
  constexpr int MT = (TN == 128) ? 4 : 2;
  constexpr int BROWS = TN / 4;  // Bs rows staged per wave
  constexpr int SM = VT ? (128 * 136) : (128 * 64 + TN * 64);
  __shared__ alignas(16) unsigned short smem[SM];
  unsigned short* As = smem;            // 128*64
  unsigned short* Bs = smem + 128 * 64; // TN*64
  int isf = flag[0];
  int outf32 = (OUTM == 1) || (OUTM == 2 && isf);
  int tid = threadIdx.x;
  int wave = tid >> 6, lane = tid & 63;
  int quad = lane >> 4, l16 = lane & 15, l7 = l16 & 7;
  int wm = (TN == 128) ? (wave >> 1) : wave;
  int wn = (TN == 128) ? (wave & 1) : 0;
  size_t m0 = (size_t)blockIdx.x * 128;
  size_t n0 = (size_t)blockIdx.y * TN;

  int lrow = lane >> 3;                 // 0..7
  int gcol = 8 * ((lane & 7) ^ lrow);   // swizzled source chunk (shorts)

  const unsigned short* ag = A + (m0 + wave * 32 + lrow) * K + gcol;
  const unsigned short* bg = Bt + (n0 + wave * BROWS + lrow) * K + gcol;
  unsigned short* asl = &As[(wave * 32) * 64];
  unsigned short* bsl = &Bs[(wave * BROWS) * 64];

  f32x4 acc[MT][4];
#pragma unroll
  for (int i = 0; i < MT; i++)
#pragma unroll
    for (int j = 0; j < 4; j++) acc[i][j] = {0.f, 0.f, 0.f, 0.f};

  for (int k0 = 0; k0 < K; k0 += 64) {
    __syncthreads();
#pragma unroll
    for (int c = 0; c < 4; c++)
      gld16(ag + (size_t)(8 * c) * K + k0, asl + (8 * c) * 64);
#pragma unroll
    for (int c = 0; c < BROWS / 8; c++)
      gld16(bg + (size_t)(8 * c) * K + k0, bsl + (8 * c) * 64);
    __syncthreads();
#pragma unroll
    for (int ko = 0; ko < 2; ko++) {
      int slot = ((4 * ko + quad) ^ l7) * 8;
      bfrag af[MT], bf[4];
#pragma unroll
      for (int i = 0; i < MT; i++)
        af[i] = *(const bfrag*)&As[(wm * (MT * 16) + i * 16 + l16) * 64 + slot];
#pragma unroll
      for (int j = 0; j < 4; j++)
        bf[j] = *(const bfrag*)&Bs[(wn * 64 + j * 16 + l16) * 64 + slot];
#pragma unroll
      for (int i = 0; i < MT; i++)
#pragma unroll
        for (int j = 0; j < 4; j++)
          acc[i][j] = __builtin_amdgcn_mfma_f32_16x16x32_bf16(bf[j], af[i], acc[i][j], 0, 0, 0);
    }
  }
  // swapped layout: m = m0+wm*(MT*16)+i*16+l16 ; n = n0+wn*64+j*16+quad*4+r
  if (VT && n0 >= 1024) {
    // V third of QKV: transpose 128x128 panel through LDS, then write
    // vbt[(b*8+hh)*64+d][s] with 64B-contiguous segments along s.
    __syncthreads();  // all waves done reading As/Bs (smem reuse)
#pragma unroll
    for (int j = 0; j < 4; j++) {
      int nl = wn * 64 + j * 16 + quad * 4;
      float4 bv = *(const float4*)&bias[n0 + nl];
#pragma unroll
      for (int i = 0; i < MT; i++) {
        int ml = wm * (MT * 16) + i * 16 + l16;
        smem[(nl + 0) * 136 + ml] = f2bf(acc[i][j][0] + bv.x);
        smem[(nl + 1) * 136 + ml] = f2bf(acc[i][j][1] + bv.y);
        smem[(nl + 2) * 136 + ml] = f2bf(acc[i][j][2] + bv.z);
        smem[(nl + 3) * 136 + ml] = f2bf(acc[i][j][3] + bv.w);
      }
    }
    __syncthreads();
    int b_ = (int)(m0 >> 11);
    int sbase = (int)(m0 & 2047);
    int rel0 = (int)n0 - 1024;
#pragma unroll
    for (int it2 = 0; it2 < 8; it2++) {
      int nl = (tid >> 2) + 64 * (it2 & 1);
      int mc = (tid & 3) + 4 * (it2 >> 1);
      int rel = rel0 + nl;
      size_t row = ((size_t)(b_ * 8 + (rel >> 6)) * 64 + (rel & 63)) * 2048;
      us8 v = *(const us8*)&smem[nl * 136 + mc * 8];
      *(us8*)&vbt[row + sbase + mc * 8] = v;
    }
    return;
  }
#pragma unroll
  for (int j = 0; j < 4; j++) {
    int nl = wn * 64 + j * 16 + quad * 4;
    size_t n = n0 + nl;
    float4 bv = *(const float4*)&bias[n];
#pragma unroll
    for (int i = 0; i < MT; i++) {
      size_t m = m0 + wm * (MT * 16) + i * 16 + l16;
      size_t off = m * N + n;
      float v0 = acc[i][j][0] + bv.x;
      float v1 = acc[i][j][1] + bv.y;
      float v2 = acc[i][j][2] + bv.z;
      float v3 = acc[i][j][3] + bv.w;
      if (QSC && n < 512) {
        v0 *= 0.18033688f; v1 *= 0.18033688f;
        v2 *= 0.18033688f; v3 *= 0.18033688f;
      }
      if (RELU) {
        v0 = fmaxf(v0, 0.0f); v1 = fmaxf(v1, 0.0f);
        v2 = fmaxf(v2, 0.0f); v3 = fmaxf(v3, 0.0f);
      }
      if (RES == 1) {
        if (isf) {
          float4 rr = *(const float4*)&((const float*)res)[off];
          v0 += rr.x; v1 += rr.y; v2 += rr.z; v3 += rr.w;
        } else {
          us4 rr = *(const us4*)&((const unsigned short*)res)[off];
          v0 += bf2f(rr[0]); v1 += bf2f(rr[1]);
          v2 += bf2f(rr[2]); v3 += bf2f(rr[3]);
        }
      } else if (RES == 2) {
        float4 rr = *(const float4*)&((const float*)res)[off];
        v0 += rr.x; v1 += rr.y; v2 += rr.z; v3 += rr.w;
      }
      if (outf32) {
        float4 o4 = {v0, v1, v2, v3};
        *(float4*)&((float*)outp)[off] = o4;
      } else {
        us4 o4 = {f2bf(v0), f2bf(v1), f2bf(v2), f2bf(v3)};
        *(us4*)&((unsigned short*)outp)[off] = o4;
      }
    }
  }
}

// ---------------- flash attention: 64q/wave, key-split, 8 waves ---------
// R7-proven kernel (53us). 256 blocks x 512 thr, 8 waves = 4 q-subblocks
// x 2 key-halves, 64 q/wave. Q pre-scaled by 0.125*log2e in QKV gemm ->
// softmax = exp2(pacc). Key-split merge via LDS (exact, no-max softmax).
// XCD chunk: 4 bh/XCD (2MB L2 set; K/V ARE HBM/L2-sensitive, unlike GEMM).
__global__ __launch_bounds__(512) void attn_k(
    const unsigned short* __restrict__ qkb,  // [8192][1536] q|k|v (q scaled)
    const unsigned short* __restrict__ vbt,  // [32*64][2048] = V^T per bh
    const int* __restrict__ mask,
    unsigned short* __restrict__ ctx) {      // [8192][512]
  constexpr int S = 2048;
  __shared__ alignas(16) unsigned short Kt[2][2][64 * 64];  // [kh][buf] 32 KB
  __shared__ alignas(16) unsigned short Vt[2][2][64 * 64];  // [kh][buf] 32 KB
  __shared__ alignas(16) float mskf[S];                     // 8 KB
  __shared__ float ml[2][256];                              // 2 KB
  __shared__ int s_all;
  int tid = threadIdx.x, wave = tid >> 6, lane = tid & 63;
  int kh = wave >> 2, wv = wave & 3;
  int l32 = lane & 31, hi = lane >> 5;

  // XCD-aware work mapping (256 blocks, 8 XCDs round-robin by linear id)
  int lin = blockIdx.x;
  int work = (lin & 7) * 32 + (lin >> 3);
  int bh = work >> 3;          // 0..31 (4 consecutive bh per XCD)
  int q0 = (work & 7) * 256;   // 0..1792
  int b = bh >> 3, h = bh & 7;
  size_t rowbase = (size_t)b * S;

  // Q fragments (B-operand), 2 q-groups of 32: col=q=l32, k(d)=16ds+8hi+j
  bfrag qf[2][4];
#pragma unroll
  for (int qg = 0; qg < 2; qg++) {
    const unsigned short* qp =
        qkb + (rowbase + q0 + wv * 64 + qg * 32 + l32) * 1536 + h * 64 + hi * 8;
#pragma unroll
    for (int ds = 0; ds < 4; ds++) qf[qg][ds] = *(const bfrag*)(qp + ds * 16);
  }

  int srow_l = lane >> 3;  // 0..7; equals (staged row)&7 -> swizzle const/lane
  int sc = lane & 7;
  int swz = (sc ^ srow_l) * 8;
  const unsigned short* kgb = qkb + 512 + h * 64;
  const unsigned short* vgb = vbt + (size_t)bh * 64 * S;

  // staging pointers (strength-reduced); wave stages 16 rows of its half
  const unsigned short* kp[2];
  const unsigned short* vp[2];
#pragma unroll
  for (int i = 0; i < 2; i++) {
    int r = wv * 16 + i * 8 + srow_l;
    kp[i] = kgb + (rowbase + kh * 1024 + r) * 1536 + swz;
    vp[i] = vgb + (size_t)r * S + kh * 1024 + swz;
  }

  auto STAGE = [&](int buf) {
#pragma unroll
    for (int i = 0; i < 2; i++) {
      gld16(kp[i], &Kt[kh][buf][(wv * 16 + i * 8) * 64]);
      kp[i] += 64 * 1536;
      gld16(vp[i], &Vt[kh][buf][(wv * 16 + i * 8) * 64]);
      vp[i] += 64;
    }
  };

  f32x16 o[4];  // [qg*2+dt]
#pragma unroll
  for (int i = 0; i < 4; i++)
#pragma unroll
    for (int j = 0; j < 16; j++) o[i][j] = 0.f;
  float l_i[2] = {0.f, 0.f};

  STAGE(0);
  if (tid == 0) s_all = 1;
  __syncthreads();
  {
    int ok = 1;
    for (int i = tid; i < S; i += 512) {
      int mv = mask[rowbase + i];
      ok &= (mv != 0);
      mskf[i] = mv ? 0.0f : -1e5f;
    }
    atomicAnd(&s_all, ok);
  }
  __syncthreads();  // tile 0 + mask + s_all ready
  int am = s_all;

  auto BODY = [&](auto amc) {
    constexpr bool AM = decltype(amc)::value;
    for (int it = 0; it < 16; it++) {
      int cur = it & 1;
      if (it + 1 < 16) STAGE(cur ^ 1);  // in flight across whole compute

#pragma unroll
      for (int qg = 0; qg < 2; qg++) {
#pragma unroll
        for (int t = 0; t < 2; t++) {
          // ---- QK^T (swapped): pacc = D[key in sub-tile t][q] ----
          f32x16 pacc;
          {
            int r = t * 32 + l32;
            f32x16 z = {};
#pragma unroll
            for (int ds = 0; ds < 4; ds++) {
              int phys = ((2 * ds + hi) ^ (l32 & 7)) * 8;
              bfrag kf = *(const bfrag*)&Kt[kh][cur][r * 64 + phys];
              pacc = __builtin_amdgcn_mfma_f32_32x32x16_bf16(
                  kf, qf[qg][ds], ds == 0 ? z : pacc, 0, 0, 0);
            }
          }
          // ---- softmax (Q pre-scaled): key=(reg&3)+8*(reg>>2)+4*hi+32t --
          unsigned pb[8];
#pragma unroll
          for (int g = 0; g < 4; g++) {
            float p0, p1, p2, p3;
            if constexpr (AM) {
              p0 = __builtin_amdgcn_exp2f(pacc[g * 4 + 0]);
              p1 = __builtin_amdgcn_exp2f(pacc[g * 4 + 1]);
              p2 = __builtin_amdgcn_exp2f(pacc[g * 4 + 2]);
              p3 = __builtin_amdgcn_exp2f(pacc[g * 4 + 3]);
            } else {
              float4 m4 =
                  *(const float4*)&mskf[kh * 1024 + it * 64 + t * 32 + g * 8 + hi * 4];
              p0 = __builtin_amdgcn_exp2f(pacc[g * 4 + 0] + m4.x);
              p1 = __builtin_amdgcn_exp2f(pacc[g * 4 + 1] + m4.y);
              p2 = __builtin_amdgcn_exp2f(pacc[g * 4 + 2] + m4.z);
              p3 = __builtin_amdgcn_exp2f(pacc[g * 4 + 3] + m4.w);
            }
            l_i[qg] += (p0 + p1) + (p2 + p3);
            pb[g * 2] = cvtpk_bf16(p0, p1);
            pb[g * 2 + 1] = cvtpk_bf16(p2, p3);
          }
          // ---- PV for this sub-tile: ks = 2t+e ----
#pragma unroll
          for (int e = 0; e < 2; e++) {
            u32x2 sA = __builtin_amdgcn_permlane32_swap(
                pb[4 * e + 0], pb[4 * e + 2], false, false);
            u32x2 sB = __builtin_amdgcn_permlane32_swap(
                pb[4 * e + 1], pb[4 * e + 3], false, false);
            u32x4 pw = {sA.x, sB.x, sA.y, sB.y};
            bfrag pf = __builtin_bit_cast(bfrag, pw);
            int ks = 2 * t + e;
#pragma unroll
            for (int dt = 0; dt < 2; dt++) {
              int r = dt * 32 + l32;
              int phys = ((2 * ks + hi) ^ (l32 & 7)) * 8;
              bfrag vf = *(const bfrag*)&Vt[kh][cur][r * 64 + phys];
              o[qg * 2 + dt] = __builtin_amdgcn_mfma_f32_32x32x16_bf16(
                  pf, vf, o[qg * 2 + dt], 0, 0, 0);
            }
          }
        }
      }
      __syncthreads();  // next tile staged + all reads of cur done
    }
  };
  if (am) BODY(std::integral_constant<bool, true>{});
  else    BODY(std::integral_constant<bool, false>{});

  // ---- merge halves through LDS, normalize, store ----
#pragma unroll
  for (int qg = 0; qg < 2; qg++) {
    unsigned lu = __builtin_bit_cast(unsigned, l_i[qg]);
    u32x2 lr = __builtin_amdgcn_permlane32_swap(lu, lu, false, false);
    float l_tot = __builtin_bit_cast(float, lr.x) + __builtin_bit_cast(float, lr.y);
    if (lane < 32) ml[kh][wv * 64 + qg * 32 + l32] = l_tot;
  }
  float* mrgK = (float*)&Kt[0][0][0];  // 32 KB: 256q x 32d (dt=0), K dead
  float* mrgV = (float*)&Vt[0][0][0];  // 32 KB: 256q x 32d (dt=1), V dead
  if (kh == 1) {
#pragma unroll
    for (int qg = 0; qg < 2; qg++) {
#pragma unroll
      for (int reg = 0; reg < 16; reg++) {
        int ql = (reg & 3) + 8 * (reg >> 2) + 4 * hi;
        int qi = wv * 64 + qg * 32 + ql;
        mrgK[qi * 32 + l32] = o[qg * 2 + 0][reg];
        mrgV[qi * 32 + l32] = o[qg * 2 + 1][reg];
      }
    }
  }
  __syncthreads();
  if (kh == 0) {
#pragma unroll
    for (int qg = 0; qg < 2; qg++) {
#pragma unroll
      for (int reg = 0; reg < 16; reg++) {
        int ql = (reg & 3) + 8 * (reg >> 2) + 4 * hi;
        int qi = wv * 64 + qg * 32 + ql;
        float inv = 1.0f / fmaxf(ml[0][qi] + ml[1][qi], 1e-30f);
        size_t qrow = rowbase + q0 + qi;
        float v0 = (o[qg * 2 + 0][reg] + mrgK[qi * 32 + l32]) * inv;
        float v1 = (o[qg * 2 + 1][reg] + mrgV[qi * 32 + l32]) * inv;
        ctx[qrow * 512 + h * 64 + l32] = f2bf(v0);
        ctx[qrow * 512 + h * 64 + 32 + l32] = f2bf(v1);
      }
    }
  }
}

extern "C" void kernel_launch(void* const* d_in, const int* in_sizes, int n_in,
                              void* d_out, int out_size, void* d_ws, size_t ws_size,
                              hipStream_t stream) {
  const unsigned short* x = (const unsigned short*)d_in[0];
  const int* mask         = (const int*)d_in[1];
  const void* wq = d_in[2];  const void* bq = d_in[3];
  const void* wk = d_in[4];  const void* bk = d_in[5];
  const void* wv = d_in[6];  const void* bv = d_in[7];
  const void* wo = d_in[8];  const void* bo = d_in[9];
  const void* w1 = d_in[10]; const void* b1 = d_in[11];
  const void* w2 = d_in[12]; const void* b2 = d_in[13];
  const void* alpha1 = d_in[14]; const void* beta1 = d_in[15];
  const void* alpha2 = d_in[16]; const void* beta2 = d_in[17];

  char* ws = (char*)d_ws;
  int* flag            = (int*)(ws + 0);
  unsigned short* wqkvT= (unsigned short*)(ws + 65536);    // [1536][512]
  unsigned short* woT  = (unsigned short*)(ws + 1638400);
  unsigned short* w1T  = (unsigned short*)(ws + 2162688);  // [2048][512]
  unsigned short* w2T  = (unsigned short*)(ws + 4259840);  // [512][2048]
  float*          bcat = (float*)         (ws + 6356992);  // 4608 f32
  float*          x1   = (float*)         (ws + 6422528);  // [8192][512] f32
  unsigned short* n1   = (unsigned short*)(ws + 23199744); // also ctx, n2
  unsigned short* qkb  = (unsigned short*)(ws + 31588352); // [8192][1536]
  unsigned short* vbt  = (unsigned short*)(ws + 56754176); // [2048][2048]
  unsigned short* ff1  = qkb;                              // [8192][2048] overlay

  dim3 blk(256);

  setup_k<<<5138, blk, 0, stream>>>(x, wq, wk, wv, wo, w1, w2,
                                    wqkvT, woT, w1T, w2T,
                                    bq, bk, bv, bo, b1, b2, bcat,
                                    alpha1, beta1, n1, flag);
  // fused QKV (Q cols scaled; V third transposed via LDS direct to vbt)
  gemm2_k<128, 0, 0, 0, 1, 1><<<dim3(64, 12), blk, 0, stream>>>(n1, wqkvT, bcat, nullptr, qkb, vbt, 1536, 512, flag);
  attn_k<<<256, dim3(512), 0, stream>>>(qkb, vbt, mask, n1);
  // out projection + residual(x) -> x1 f32
  gemm2_k<64, 1, 1, 0, 0, 0><<<dim3(64, 8), blk, 0, stream>>>(n1, woT, bcat + 1536, (const void*)x, x1, nullptr, 512, 512, flag);
  norm2_k<<<2048, blk, 0, stream>>>(x1, alpha2, beta2, n1, flag);
  // ffn1 + relu -> ff1
  gemm2_k<128, 0, 0, 1, 0, 0><<<dim3(64, 16), blk, 0, stream>>>(n1, w1T, bcat + 2048, nullptr, ff1, nullptr, 2048, 512, flag);
  // ffn2 + residual(x1) -> d_out
  gemm2_k<64, 2, 2, 0, 0, 0><<<dim3(64, 8), blk, 0, stream>>>(ff1, w2T, bcat + 4096, x1, d_out, nullptr, 512, 2048, flag);
}